// Round 6
// baseline (578.700 us; speedup 1.0000x reference)
//
#include <hip/hip_runtime.h>
#include <hip/hip_bf16.h>
#include <math.h>

typedef __attribute__((ext_vector_type(8))) short short8;
typedef __attribute__((ext_vector_type(4))) float f32x4;

#define MFMA_BF16 __builtin_amdgcn_mfma_f32_16x16x32_bf16

__device__ __forceinline__ ushort f2bf(float f) {
  union { __hip_bfloat16 h; ushort u; } c;
  c.h = __float2bfloat16(f);
  return c.u;
}
__device__ __forceinline__ void async_cp16(const ushort* g, ushort* l) {
  __builtin_amdgcn_global_load_lds(
      (const __attribute__((address_space(1))) void*)g,
      (__attribute__((address_space(3))) void*)l, 16, 0, 0);
}

// ------------- fused weight fp32->bf16 conversion + bias concat (one launch) -------------
__global__ __launch_bounds__(256) void conv_all(
    const float* __restrict__ Wq, const float* __restrict__ Wk,
    const float* __restrict__ Wv, const float* __restrict__ Wo,
    const float* __restrict__ W1, const float* __restrict__ W2,
    const float* __restrict__ bq, const float* __restrict__ bk,
    const float* __restrict__ bv,
    ushort* __restrict__ wqkv, ushort* __restrict__ wo,
    ushort* __restrict__ w1, ushort* __restrict__ w2,
    float* __restrict__ bqkv) {
  int i = blockIdx.x * 256 + threadIdx.x;   // float4 index
  if (i < 3145728) {
    const float* src; ushort* dst; int off;
    if (i < 786432)        { // Wq|Wk|Wv -> concatenated wqkv [3072,1024]
      dst = wqkv; off = i;
      if (i < 262144)      src = Wq + (size_t)i * 4;
      else if (i < 524288) src = Wk + (size_t)(i - 262144) * 4;
      else                 src = Wv + (size_t)(i - 524288) * 4;
    } else if (i < 1048576) { dst = wo; off = i - 786432;  src = Wo + (size_t)off * 4; }
    else if (i < 2097152)   { dst = w1; off = i - 1048576; src = W1 + (size_t)off * 4; }
    else                    { dst = w2; off = i - 2097152; src = W2 + (size_t)off * 4; }
    float4 v = *(const float4*)src;
    ushort4 o;
    o.x = f2bf(v.x); o.y = f2bf(v.y); o.z = f2bf(v.z); o.w = f2bf(v.w);
    ((ushort4*)dst)[off] = o;
  } else if (i < 3146496) {  // biases: 3 x 256 float4
    int off = i - 3145728;
    const float* src;
    if (off < 256)      src = bq + (size_t)off * 4;
    else if (off < 512) src = bk + (size_t)(off - 256) * 4;
    else                src = bv + (size_t)(off - 512) * 4;
    ((float4*)bqkv)[off] = *(const float4*)src;
  }
}

// ---------------- layernorm: one block per 1024-float row -> bf16 ----------------
__global__ __launch_bounds__(256) void ln_kernel(const float* __restrict__ x,
    const float* __restrict__ g, const float* __restrict__ b,
    ushort* __restrict__ out) {
  const int row = blockIdx.x, t = threadIdx.x;
  float4 v = ((const float4*)(x + (size_t)row * 1024))[t];
  float s  = v.x + v.y + v.z + v.w;
  float ss = v.x*v.x + v.y*v.y + v.z*v.z + v.w*v.w;
  #pragma unroll
  for (int off = 32; off >= 1; off >>= 1) {
    s  += __shfl_xor(s, off);
    ss += __shfl_xor(ss, off);
  }
  __shared__ float red[8];
  int wv = t >> 6, ln = t & 63;
  if (ln == 0) { red[wv] = s; red[4 + wv] = ss; }
  __syncthreads();
  float S  = red[0] + red[1] + red[2] + red[3];
  float SS = red[4] + red[5] + red[6] + red[7];
  float mu  = S * (1.0f/1024.0f);
  float var = SS * (1.0f/1024.0f) - mu*mu;
  float rs  = rsqrtf(var + 1e-6f);
  float4 gv = ((const float4*)g)[t];
  float4 bv = ((const float4*)b)[t];
  ushort4 o;
  o.x = f2bf((v.x-mu)*rs*gv.x + bv.x);
  o.y = f2bf((v.y-mu)*rs*gv.y + bv.y);
  o.z = f2bf((v.z-mu)*rs*gv.z + bv.z);
  o.w = f2bf((v.w-mu)*rs*gv.w + bv.w);
  ((ushort4*)(out + (size_t)row*1024))[t] = o;
}

enum { EPI_QK = 0, EPI_VT = 1, EPI_WO = 2, EPI_GELU = 3, EPI_OUT = 4 };

// ---------------- pipelined bf16 GEMM: BMx256 tile, BK=32, 4 LDS buffers ----------------
// One barrier + one COUNTED vmcnt per K-32 iteration (no lgkm drain, no 2nd barrier):
//   iter j: issue stage(j+2)->buf[(j+2)%4]; ds_read buf[j%4]; MFMA; vmcnt(LPS); barrier.
// Ledger: RAW buf[j+1]: iter j's vmcnt(LPS) leaves only stage(j+2)'s LPS loads
//   outstanding -> stage(j+1) landed; barrier makes it collective.
// WAR buf[(j+2)%4]: its last readers ran in iter j-2, separated by the barriers at the
//   ends of iters j-2 and j-1 (reads are serviced before that wave's MFMAs/barrier).
// Tail (j+2>=NT): vmcnt(0) (stage(j+1) is newest outstanding; counted wait can't see it).
// Swizzle (both sides): row = 4 chunks of 16B; LDS pos p holds global chunk p^(row&3);
//   reads use quad^(row&3). Verified 8 words/bank on read; gload_lds dest stays linear
//   (base + lane*16B within each wave) with pre-swizzled global source.
template <int EPI, int MR>   // BM = 32*MR (MR=8: 256x256, MR=4: 128x256), BN=256
__global__ __launch_bounds__(512, 2) void gemm_pipe(const ushort* __restrict__ A,
    const ushort* __restrict__ Bw, const float* __restrict__ bias,
    const float* __restrict__ res, void* __restrict__ outp,
    void* __restrict__ outp2, int K, int N, float scale) {
  constexpr int BM  = 32 * MR;
  constexpr int ACH = (BM * 4) / 512;      // A chunks/thread/K-tile: MR=8->2, MR=4->1
  constexpr int LPS = ACH + 2;             // loads per stage per thread (B adds 2)
  __shared__ ushort As[4][BM * 32];        // MR=8: 64 KB, MR=4: 32 KB
  __shared__ ushort Bs[4][256 * 32];       // 64 KB
  const int t = threadIdx.x;
  const int lane = t & 63, wave = t >> 6;
  const int col = lane & 15, quad = lane >> 4;
  const int m0 = blockIdx.x * BM, n0 = blockIdx.y * 256;
  const int wm = wave >> 2, wn = wave & 3;   // 2 x 4 waves; per-wave out (BM/2) x 64

  f32x4 acc[MR][4];
  #pragma unroll
  for (int i = 0; i < MR; i++)
    #pragma unroll
    for (int j = 0; j < 4; j++) acc[i][j] = (f32x4){0.f, 0.f, 0.f, 0.f};

  // staging plan: chunk c -> row = c>>2, pos p = c&3, global chunk = p^(row&3)
  size_t aoff[ACH]; int adst[ACH];
  size_t boff[2];   int bdst[2];
  #pragma unroll
  for (int i = 0; i < ACH; i++) {
    int c = i * 512 + t, row = c >> 2, p = c & 3;
    aoff[i] = (size_t)(m0 + row) * K + (p ^ (row & 3)) * 8;
    adst[i] = c * 8;
  }
  #pragma unroll
  for (int i = 0; i < 2; i++) {
    int c = i * 512 + t, row = c >> 2, p = c & 3;
    boff[i] = (size_t)(n0 + row) * K + (p ^ (row & 3)) * 8;
    bdst[i] = c * 8;
  }

  const int NT = K >> 5;
  // prologue: stage K-tiles 0,1 into bufs 0,1; wait tile 0 only (tile 1 in flight)
  #pragma unroll
  for (int i = 0; i < ACH; i++) async_cp16(A + aoff[i], &As[0][adst[i]]);
  #pragma unroll
  for (int i = 0; i < 2;  i++) async_cp16(Bw + boff[i], &Bs[0][bdst[i]]);
  #pragma unroll
  for (int i = 0; i < ACH; i++) async_cp16(A + aoff[i] + 32, &As[1][adst[i]]);
  #pragma unroll
  for (int i = 0; i < 2;  i++) async_cp16(Bw + boff[i] + 32, &Bs[1][bdst[i]]);
  asm volatile("s_waitcnt vmcnt(%0)" :: "n"(LPS) : "memory");
  __builtin_amdgcn_sched_barrier(0);
  __builtin_amdgcn_s_barrier();
  __builtin_amdgcn_sched_barrier(0);

  for (int j = 0; j < NT; j++) {
    const int buf = j & 3;
    if (j + 2 < NT) {
      const int nb = (j + 2) & 3;
      const int ko = (j + 2) << 5;
      #pragma unroll
      for (int i = 0; i < ACH; i++) async_cp16(A + aoff[i] + ko, &As[nb][adst[i]]);
      #pragma unroll
      for (int i = 0; i < 2;  i++) async_cp16(Bw + boff[i] + ko, &Bs[nb][bdst[i]]);
    }
    short8 af[MR], bf[4];
    #pragma unroll
    for (int tm = 0; tm < MR; tm++) {
      const int row = wm * (16 * MR) + tm * 16 + col;
      af[tm] = *(const short8*)&As[buf][row * 32 + (quad ^ (row & 3)) * 8];
    }
    #pragma unroll
    for (int tn = 0; tn < 4; tn++) {
      const int row = wn * 64 + tn * 16 + col;
      bf[tn] = *(const short8*)&Bs[buf][row * 32 + (quad ^ (row & 3)) * 8];
    }
    __builtin_amdgcn_s_setprio(1);
    #pragma unroll
    for (int tm = 0; tm < MR; tm++)
      #pragma unroll
      for (int tn = 0; tn < 4; tn++)
        acc[tm][tn] = MFMA_BF16(af[tm], bf[tn], acc[tm][tn], 0, 0, 0);
    __builtin_amdgcn_s_setprio(0);
    if (j + 2 < NT) {
      asm volatile("s_waitcnt vmcnt(%0)" :: "n"(LPS) : "memory");
    } else {
      asm volatile("s_waitcnt vmcnt(0)" ::: "memory");
    }
    __builtin_amdgcn_sched_barrier(0);
    __builtin_amdgcn_s_barrier();
    __builtin_amdgcn_sched_barrier(0);
  }

  #pragma unroll
  for (int tm = 0; tm < MR; tm++) {
    #pragma unroll
    for (int tn = 0; tn < 4; tn++) {
      const int n = n0 + wn * 64 + tn * 16 + col;
      #pragma unroll
      for (int r = 0; r < 4; r++) {
        const int m = m0 + wm * (16 * MR) + tm * 16 + quad * 4 + r;
        float v = acc[tm][tn][r];
        if (EPI == EPI_QK) {
          v += bias[n];
          int nl = n & 1023, h = nl >> 6, hd = nl & 63;
          int bb = m >> 11, s2 = m & 2047;
          if (n < 1024)
            ((ushort*)outp)[(((size_t)(bb * 16 + h) * 2048 + s2) * 64) + hd] = f2bf(v * scale);
          else
            ((ushort*)outp2)[(((size_t)(bb * 16 + h) * 2048 + s2) * 64) + hd] = f2bf(v);
        } else if (EPI == EPI_GELU) {
          v += bias[n];
          float u = v * 0.7978845608028654f * (1.0f + 0.044715f * v * v);
          float e = __builtin_amdgcn_exp2f(u * 2.885390081777927f);  // e^{2u}
          float th = 1.0f - 2.0f * __builtin_amdgcn_rcpf(e + 1.0f);
          ((ushort*)outp)[(size_t)m * N + n] = f2bf(0.5f * v * (1.0f + th));
        } else if (EPI == EPI_VT) {
          // A=Wv (m = v-dim), Bw=xn (n = token); bias indexed by m
          float vv = v + bias[m];
          int h = m >> 6, hd = m & 63, bb = n >> 11, s2 = n & 2047;
          ((ushort*)outp)[((size_t)((bb * 16 + h) * 64 + hd)) * 2048 + s2] = f2bf(vv);
        } else {  // EPI_WO / EPI_OUT: float out + bias + residual
          ((float*)outp)[(size_t)m * N + n] = v + bias[n] + res[(size_t)m * N + n];
        }
      }
    }
  }
}

// ---------------- flash attention v11 (unchanged from R5: 113 us stable) ----------
__global__ __launch_bounds__(256) void attn_kernel(const ushort* __restrict__ Qb,
    const ushort* __restrict__ Kb, const ushort* __restrict__ Vt,
    ushort* __restrict__ ctx) {
  const int lane = threadIdx.x & 63, wave = threadIdx.x >> 6;
  const int col = lane & 15, quad = lane >> 4;
  const int bx = blockIdx.x;
  const int bh = bx & 63;          // XCD = bh % 8 for every q-tile of this head
  const int qt = bx >> 6;          // 0..15
  const int qbase = qt * 128 + wave * 32;
  const ushort* Qh = Qb + (size_t)bh * 2048 * 64;
  const ushort* Kh = Kb + (size_t)bh * 2048 * 64;
  const ushort* Vh = Vt + (size_t)bh * 64 * 2048;

  short8 qa[2][2];
  #pragma unroll
  for (int qg = 0; qg < 2; qg++) {
    const ushort* Qr = Qh + (size_t)(qbase + qg * 16 + col) * 64 + quad * 8;
    qa[qg][0] = *(const short8*)Qr;
    qa[qg][1] = *(const short8*)(Qr + 32);
  }

  f32x4 Ot[2][4];
  float l_part[2];
  #pragma unroll
  for (int qg = 0; qg < 2; qg++) {
    l_part[qg] = 0.f;
    #pragma unroll
    for (int dt = 0; dt < 4; dt++) Ot[qg][dt] = (f32x4){0.f, 0.f, 0.f, 0.f};
  }

  __shared__ ushort Ks[2][2][64 * 32];   // [buf][d-half][key*32 + swz-chunk] 16 KB
  __shared__ ushort Vs[2][2][64 * 32];   // [buf][key-half][d*32 + swz-chunk] 16 KB
  __shared__ ushort P_lds[4][16][64];    // [wave][q][8 x 16B chunks, swz] 8 KB

  const int lrow = lane >> 2;
  const int srow = wave * 16 + lrow;                       // row this lane stages
  const int lcol = ((lane & 3) ^ ((srow >> 1) & 3)) * 8;   // swizzled 16B chunk in 64B half
  const ushort* Kg = Kh + (size_t)srow * 64 + lcol;        // + kb*64 (+32 for half 1)
  const ushort* Vg = Vh + (size_t)srow * 2048 + lcol;      // + kb   (+32 for half 1)
  const int so = (wave * 16) * 32;

  const int kvswz = (col >> 1) & 3;   // fragment-read XOR (rows kt*16+col: (row>>1)&3)
  const int pswz = col & 7;           // P chunk XOR

  // prologue: stage chunk 0 into buf 0
  async_cp16(Kg,      &Ks[0][0][so]);
  async_cp16(Kg + 32, &Ks[0][1][so]);
  async_cp16(Vg,      &Vs[0][0][so]);
  async_cp16(Vg + 32, &Vs[0][1][so]);
  __syncthreads();

  int cur = 0;
  for (int kb = 0; kb < 2048; kb += 64) {
    if (kb + 64 < 2048) {
      const int nxt = cur ^ 1;
      async_cp16(Kg + (size_t)(kb + 64) * 64,      &Ks[nxt][0][so]);
      async_cp16(Kg + (size_t)(kb + 64) * 64 + 32, &Ks[nxt][1][so]);
      async_cp16(Vg + (kb + 64),                   &Vs[nxt][0][so]);
      async_cp16(Vg + (kb + 64) + 32,              &Vs[nxt][1][so]);
    }

    // fragments from LDS (shared across the 2 q-groups), swizzled reads
    short8 kf[4][2], vf[4][2];
    #pragma unroll
    for (int kt = 0; kt < 4; kt++)
      #pragma unroll
      for (int c = 0; c < 2; c++)
        kf[kt][c] = *(const short8*)&Ks[cur][c][(kt * 16 + col) * 32 + (quad ^ kvswz) * 8];
    #pragma unroll
    for (int dt = 0; dt < 4; dt++)
      #pragma unroll
      for (int c = 0; c < 2; c++)
        vf[dt][c] = *(const short8*)&Vs[cur][c][(dt * 16 + col) * 32 + (quad ^ kvswz) * 8];

    #pragma unroll
    for (int qg = 0; qg < 2; qg++) {
      f32x4 s[4];
      __builtin_amdgcn_s_setprio(1);
      #pragma unroll
      for (int kt = 0; kt < 4; kt++) {
        s[kt] = (f32x4){0.f, 0.f, 0.f, 0.f};
        s[kt] = MFMA_BF16(kf[kt][0], qa[qg][0], s[kt], 0, 0, 0);
        s[kt] = MFMA_BF16(kf[kt][1], qa[qg][1], s[kt], 0, 0, 0);
      }
      __builtin_amdgcn_s_setprio(0);
      ushort(*P)[64] = P_lds[wave];
      #pragma unroll
      for (int kt = 0; kt < 4; kt++) {
        float p0 = __builtin_amdgcn_exp2f(s[kt][0]);
        float p1 = __builtin_amdgcn_exp2f(s[kt][1]);
        float p2 = __builtin_amdgcn_exp2f(s[kt][2]);
        float p3 = __builtin_amdgcn_exp2f(s[kt][3]);
        l_part[qg] += (p0 + p1) + (p2 + p3);
        uint2 pk;
        asm("v_cvt_pk_bf16_f32 %0, %1, %2" : "=v"(pk.x) : "v"(p0), "v"(p1));
        asm("v_cvt_pk_bf16_f32 %0, %1, %2" : "=v"(pk.y) : "v"(p2), "v"(p3));
        *(uint2*)&P[col][(((2 * kt + (quad >> 1)) ^ pswz) * 8) + (quad & 1) * 4] = pk;
      }
      // PV for this qg (same-wave LDS RAW handled in-order; no barrier needed)
      #pragma unroll
      for (int c = 0; c < 2; c++) {
        short8 pf = *(const short8*)&P_lds[wave][col][((4 * c + quad) ^ pswz) * 8];
        __builtin_amdgcn_s_setprio(1);
        #pragma unroll
        for (int dt = 0; dt < 4; dt++)
          Ot[qg][dt] = MFMA_BF16(vf[dt][c], pf, Ot[qg][dt], 0, 0, 0);
        __builtin_amdgcn_s_setprio(0);
      }
    }
    __syncthreads();
    cur ^= 1;
  }

  const int bb = bh >> 4, h = bh & 15;
  #pragma unroll
  for (int qg = 0; qg < 2; qg++) {
    float l = l_part[qg];
    l += __shfl_xor(l, 16);
    l += __shfl_xor(l, 32);
    float inv = __builtin_amdgcn_rcpf(l);
    const int q = qbase + qg * 16 + col;
    size_t base = ((size_t)(bb * 2048 + q)) * 1024 + h * 64;
    #pragma unroll
    for (int dt = 0; dt < 4; dt++) {
      ushort4 o;
      o.x = f2bf(Ot[qg][dt][0] * inv);
      o.y = f2bf(Ot[qg][dt][1] * inv);
      o.z = f2bf(Ot[qg][dt][2] * inv);
      o.w = f2bf(Ot[qg][dt][3] * inv);
      *(ushort4*)&ctx[base + dt * 16 + quad * 4] = o;
    }
  }
}

// ---------------- host ----------------
extern "C" void kernel_launch(void* const* d_in, const int* in_sizes, int n_in,
                              void* d_out, int out_size, void* d_ws, size_t ws_size,
                              hipStream_t stream) {
  const float* x     = (const float*)d_in[0];
  const float* Wq    = (const float*)d_in[1];
  const float* bq    = (const float*)d_in[2];
  const float* Wk    = (const float*)d_in[3];
  const float* bk    = (const float*)d_in[4];
  const float* Wv    = (const float*)d_in[5];
  const float* bv    = (const float*)d_in[6];
  const float* Wo    = (const float*)d_in[7];
  const float* bo    = (const float*)d_in[8];
  const float* W1    = (const float*)d_in[9];
  const float* b1    = (const float*)d_in[10];
  const float* W2    = (const float*)d_in[11];
  const float* b2    = (const float*)d_in[12];
  const float* ln1_g = (const float*)d_in[13];
  const float* ln1_b = (const float*)d_in[14];
  const float* ln2_g = (const float*)d_in[15];
  const float* ln2_b = (const float*)d_in[16];

  const size_t MB = 1ull << 20;
  char* ws = (char*)d_ws;
  ushort* Wqkv_b = (ushort*)(ws + 0 * MB);    // 6 MB  [3072,1024] (Q|K|V)
  ushort* Wo_b   = (ushort*)(ws + 6 * MB);    // 2 MB
  ushort* W1_b   = (ushort*)(ws + 8 * MB);    // 8 MB
  ushort* W2_b   = (ushort*)(ws + 16 * MB);   // 8 MB
  ushort* xn1    = (ushort*)(ws + 24 * MB);   // 16 MB
  ushort* Qb     = (ushort*)(ws + 40 * MB);   // 16 MB
  ushort* Kb     = (ushort*)(ws + 56 * MB);   // 16 MB
  ushort* Vt     = (ushort*)(ws + 72 * MB);   // 16 MB
  ushort* ctxb   = (ushort*)(ws + 88 * MB);   // 16 MB
  float*  x2     = (float*)(ws + 104 * MB);   // 32 MB
  ushort* xn2    = (ushort*)(ws + 136 * MB);  // 16 MB
  ushort* y1     = (ushort*)(ws + 152 * MB);  // 64 MB -> end 216 MB
  // bqkv aliases start of y1 (lifetime-disjoint: consumed before GELU GEMM writes y1)
  float*  bqkv   = (float*)(ws + 152 * MB);

  conv_all<<<12291, 256, 0, stream>>>(Wq, Wk, Wv, Wo, W1, W2, bq, bk, bv,
                                      Wqkv_b, Wo_b, W1_b, W2_b, bqkv);

  ln_kernel<<<8192, 256, 0, stream>>>(x, ln1_g, ln1_b, xn1);

  const float cs = 0.125f * 1.4426950408889634f;  // log2(e)/sqrt(64), folded into Q
  // Q|K projections (N=2048)
  gemm_pipe<EPI_QK, 8><<<dim3(32, 8), 512, 0, stream>>>(
      xn1, Wqkv_b, bqkv, nullptr, Qb, Kb, 1024, 2048, cs);
  // V^T projection: A = Wv (rows = v-dim), B = xn (rows = tokens) -> C[vdim, token]
  gemm_pipe<EPI_VT, 4><<<dim3(8, 32), 512, 0, stream>>>(
      Wqkv_b + (size_t)2048 * 1024, xn1, bqkv + 2048, nullptr, Vt, nullptr,
      1024, 8192, 1.0f);

  attn_kernel<<<1024, 256, 0, stream>>>(Qb, Kb, Vt, ctxb);

  gemm_pipe<EPI_WO, 4><<<dim3(64, 4), 512, 0, stream>>>(
      ctxb, Wo_b, bo, x, x2, nullptr, 1024, 1024, 1.0f);

  ln_kernel<<<8192, 256, 0, stream>>>(x2, ln2_g, ln2_b, xn2);

  gemm_pipe<EPI_GELU, 8><<<dim3(32, 16), 512, 0, stream>>>(
      xn2, W1_b, b1, nullptr, y1, nullptr, 1024, 4096, 1.0f);
  gemm_pipe<EPI_OUT, 4><<<dim3(64, 4), 512, 0, stream>>>(
      y1, W2_b, b2, x2, d_out, nullptr, 4096, 1024, 1.0f);
}

// Round 7
// 559.888 us; speedup vs baseline: 1.0336x; 1.0336x over previous
//
#include <hip/hip_runtime.h>
#include <hip/hip_bf16.h>
#include <math.h>

typedef __attribute__((ext_vector_type(8))) short short8;
typedef __attribute__((ext_vector_type(4))) float f32x4;

#define MFMA_BF16 __builtin_amdgcn_mfma_f32_16x16x32_bf16

__device__ __forceinline__ ushort f2bf(float f) {
  union { __hip_bfloat16 h; ushort u; } c;
  c.h = __float2bfloat16(f);
  return c.u;
}
__device__ __forceinline__ void async_cp16(const ushort* g, ushort* l) {
  __builtin_amdgcn_global_load_lds(
      (const __attribute__((address_space(1))) void*)g,
      (__attribute__((address_space(3))) void*)l, 16, 0, 0);
}

// ------------- fused weight fp32->bf16 conversion + bias concat (one launch) -------------
__global__ __launch_bounds__(256) void conv_all(
    const float* __restrict__ Wq, const float* __restrict__ Wk,
    const float* __restrict__ Wv, const float* __restrict__ Wo,
    const float* __restrict__ W1, const float* __restrict__ W2,
    const float* __restrict__ bq, const float* __restrict__ bk,
    const float* __restrict__ bv,
    ushort* __restrict__ wqkv, ushort* __restrict__ wo,
    ushort* __restrict__ w1, ushort* __restrict__ w2,
    float* __restrict__ bqkv) {
  int i = blockIdx.x * 256 + threadIdx.x;   // float4 index
  if (i < 3145728) {
    const float* src; ushort* dst; int off;
    if (i < 786432)        { // Wq|Wk|Wv -> concatenated wqkv [3072,1024]
      dst = wqkv; off = i;
      if (i < 262144)      src = Wq + (size_t)i * 4;
      else if (i < 524288) src = Wk + (size_t)(i - 262144) * 4;
      else                 src = Wv + (size_t)(i - 524288) * 4;
    } else if (i < 1048576) { dst = wo; off = i - 786432;  src = Wo + (size_t)off * 4; }
    else if (i < 2097152)   { dst = w1; off = i - 1048576; src = W1 + (size_t)off * 4; }
    else                    { dst = w2; off = i - 2097152; src = W2 + (size_t)off * 4; }
    float4 v = *(const float4*)src;
    ushort4 o;
    o.x = f2bf(v.x); o.y = f2bf(v.y); o.z = f2bf(v.z); o.w = f2bf(v.w);
    ((ushort4*)dst)[off] = o;
  } else if (i < 3146496) {  // biases: 3 x 256 float4
    int off = i - 3145728;
    const float* src;
    if (off < 256)      src = bq + (size_t)off * 4;
    else if (off < 512) src = bk + (size_t)(off - 256) * 4;
    else                src = bv + (size_t)(off - 512) * 4;
    ((float4*)bqkv)[off] = *(const float4*)src;
  }
}

// ---------------- layernorm: one block per 1024-float row -> bf16 ----------------
__global__ __launch_bounds__(256) void ln_kernel(const float* __restrict__ x,
    const float* __restrict__ g, const float* __restrict__ b,
    ushort* __restrict__ out) {
  const int row = blockIdx.x, t = threadIdx.x;
  float4 v = ((const float4*)(x + (size_t)row * 1024))[t];
  float s  = v.x + v.y + v.z + v.w;
  float ss = v.x*v.x + v.y*v.y + v.z*v.z + v.w*v.w;
  #pragma unroll
  for (int off = 32; off >= 1; off >>= 1) {
    s  += __shfl_xor(s, off);
    ss += __shfl_xor(ss, off);
  }
  __shared__ float red[8];
  int wv = t >> 6, ln = t & 63;
  if (ln == 0) { red[wv] = s; red[4 + wv] = ss; }
  __syncthreads();
  float S  = red[0] + red[1] + red[2] + red[3];
  float SS = red[4] + red[5] + red[6] + red[7];
  float mu  = S * (1.0f/1024.0f);
  float var = SS * (1.0f/1024.0f) - mu*mu;
  float rs  = rsqrtf(var + 1e-6f);
  float4 gv = ((const float4*)g)[t];
  float4 bv = ((const float4*)b)[t];
  ushort4 o;
  o.x = f2bf((v.x-mu)*rs*gv.x + bv.x);
  o.y = f2bf((v.y-mu)*rs*gv.y + bv.y);
  o.z = f2bf((v.z-mu)*rs*gv.z + bv.z);
  o.w = f2bf((v.w-mu)*rs*gv.w + bv.w);
  ((ushort4*)(out + (size_t)row*1024))[t] = o;
}

enum { EPI_QK = 0, EPI_VT = 1, EPI_WO = 2, EPI_GELU = 3, EPI_OUT = 4 };

// ---------------- 128x128 tiled bf16 GEMM (2-barrier drain structure) ----------------
// kept for VT / WO / OUT whose shapes under-occupy a 256^2 grid
template <int EPI>
__global__ __launch_bounds__(256) void gemm_kernel(const ushort* __restrict__ A,
    const ushort* __restrict__ Bw, const float* __restrict__ bias,
    const float* __restrict__ res, void* __restrict__ outp,
    void* __restrict__ outp2, int K, int N, float scale) {
  __shared__ ushort As[2][128 * 32];
  __shared__ ushort Bs[2][128 * 32];
  const int t = threadIdx.x;
  const int m0 = blockIdx.x * 128, n0 = blockIdx.y * 128;
  const int lane = t & 63, wave = t >> 6;
  const int col = lane & 15, quad = lane >> 4;
  const int wrow = (wave >> 1) * 64, wcol = (wave & 1) * 64;

  f32x4 acc[4][4];
  #pragma unroll
  for (int i = 0; i < 4; i++)
    #pragma unroll
    for (int j = 0; j < 4; j++)
      acc[i][j] = (f32x4){0.f, 0.f, 0.f, 0.f};

  const int lrow = lane >> 2, lcol = (lane & 3) * 8;
  const ushort* Ag = A  + (size_t)(m0 + wave * 32 + lrow) * K + lcol;
  const ushort* Bg = Bw + (size_t)(n0 + wave * 32 + lrow) * K + lcol;
  const int ldso = (wave * 32) * 32;

  for (int k0 = 0; k0 < K; k0 += 64) {
    __syncthreads();
    #pragma unroll
    for (int c = 0; c < 2; c++) {
      async_cp16(Ag + k0 + c * 32,                  &As[c][ldso]);
      async_cp16(Ag + (size_t)16 * K + k0 + c * 32, &As[c][ldso + 16 * 32]);
      async_cp16(Bg + k0 + c * 32,                  &Bs[c][ldso]);
      async_cp16(Bg + (size_t)16 * K + k0 + c * 32, &Bs[c][ldso + 16 * 32]);
    }
    __syncthreads();
    #pragma unroll
    for (int c = 0; c < 2; c++) {
      short8 af[4], bf[4];
      #pragma unroll
      for (int tm = 0; tm < 4; tm++)
        af[tm] = *(const short8*)&As[c][(wrow + tm * 16 + col) * 32 + quad * 8];
      #pragma unroll
      for (int tn = 0; tn < 4; tn++)
        bf[tn] = *(const short8*)&Bs[c][(wcol + tn * 16 + col) * 32 + quad * 8];
      #pragma unroll
      for (int tm = 0; tm < 4; tm++)
        #pragma unroll
        for (int tn = 0; tn < 4; tn++)
          acc[tm][tn] = MFMA_BF16(af[tm], bf[tn], acc[tm][tn], 0, 0, 0);
    }
  }

  #pragma unroll
  for (int tm = 0; tm < 4; tm++) {
    #pragma unroll
    for (int tn = 0; tn < 4; tn++) {
      const int n = n0 + wcol + tn * 16 + col;
      const float bn = (EPI == EPI_VT) ? 0.f : bias[n];
      #pragma unroll
      for (int r = 0; r < 4; r++) {
        const int m = m0 + wrow + tm * 16 + quad * 4 + r;
        float v = acc[tm][tn][r] + bn;
        if (EPI == EPI_VT) {
          // A=Wv, Bw=xn: m = v-dim, n = token. bias indexed by m.
          float vv = v + bias[m];
          int h = m >> 6, hd = m & 63, bb = n >> 11, s2 = n & 2047;
          ((ushort*)outp)[((size_t)((bb * 16 + h) * 64 + hd)) * 2048 + s2] = f2bf(vv);
        } else if (EPI == EPI_GELU) {
          float u = v * 0.7978845608028654f * (1.0f + 0.044715f * v * v);
          float e = __builtin_amdgcn_exp2f(u * 2.885390081777927f);  // e^{2u}
          float th = 1.0f - 2.0f * __builtin_amdgcn_rcpf(e + 1.0f);
          ((ushort*)outp)[(size_t)m * N + n] = f2bf(0.5f * v * (1.0f + th));
        } else {  // EPI_WO / EPI_OUT
          ((float*)outp)[(size_t)m * N + n] = v + res[(size_t)m * N + n];
        }
      }
    }
  }
}

// ---------------- 256x256 tiled bf16 GEMM, BK=64, 8 waves, counted vmcnt pipeline ------
template <int EPI>
__global__ __launch_bounds__(512, 2) void gemm256_kernel(const ushort* __restrict__ A,
    const ushort* __restrict__ Bw, const float* __restrict__ bias,
    void* __restrict__ outp, void* __restrict__ outp2, int K, int N, float scale) {
  __shared__ ushort As[2][256 * 64];   // 32 KB each buf
  __shared__ ushort Bs[2][256 * 64];
  const int t = threadIdx.x;
  const int lane = t & 63, wave = t >> 6;
  const int col = lane & 15, quad = lane >> 4;
  const int m0 = blockIdx.x * 256, n0 = blockIdx.y * 256;
  const int wm = wave >> 2, wn = wave & 3;   // 2 x 4 wave grid; per-wave out 128 x 64

  f32x4 acc[8][4];
  #pragma unroll
  for (int i = 0; i < 8; i++)
    #pragma unroll
    for (int j = 0; j < 4; j++)
      acc[i][j] = (f32x4){0.f, 0.f, 0.f, 0.f};

  // staging plan: 2048 16B-chunks per tile per operand; thread handles chunks
  // c = i*512 + t (i=0..3). row = c>>3, in-row pos p = c&7, global chunk = p^(row&7).
  size_t aoff[4], boff[4];
  int sdst[4];
  #pragma unroll
  for (int i = 0; i < 4; i++) {
    int c = i * 512 + t;
    int row = c >> 3, p = c & 7;
    int gcol = (p ^ (row & 7)) * 8;
    aoff[i] = (size_t)(m0 + row) * K + gcol;
    boff[i] = (size_t)(n0 + row) * K + gcol;
    sdst[i] = c * 8;   // ushort offset; = uniform base + lane*16B within each wave
  }

  const int NT = K >> 6;
  // prologue: stage tile 0 into buf 0
  #pragma unroll
  for (int i = 0; i < 4; i++) {
    async_cp16(A  + aoff[i], &As[0][sdst[i]]);
    async_cp16(Bw + boff[i], &Bs[0][sdst[i]]);
  }

  int cur = 0;
  for (int kt = 0; kt < NT; kt++) {
    if (kt + 1 < NT) {
      const int nxt = cur ^ 1;
      const int ko = (kt + 1) << 6;
      #pragma unroll
      for (int i = 0; i < 4; i++) {
        async_cp16(A  + aoff[i] + ko, &As[nxt][sdst[i]]);
        async_cp16(Bw + boff[i] + ko, &Bs[nxt][sdst[i]]);
      }
      asm volatile("s_waitcnt vmcnt(8)" ::: "memory");
    } else {
      asm volatile("s_waitcnt vmcnt(0)" ::: "memory");
    }
    __builtin_amdgcn_sched_barrier(0);
    __builtin_amdgcn_s_barrier();
    __builtin_amdgcn_sched_barrier(0);

    #pragma unroll
    for (int c = 0; c < 2; c++) {
      short8 af[8], bf[4];
      #pragma unroll
      for (int tm = 0; tm < 8; tm++) {
        const int row = wm * 128 + tm * 16 + col;
        af[tm] = *(const short8*)&As[cur][row * 64 + ((c * 4 + quad) ^ (row & 7)) * 8];
      }
      #pragma unroll
      for (int tn = 0; tn < 4; tn++) {
        const int row = wn * 64 + tn * 16 + col;
        bf[tn] = *(const short8*)&Bs[cur][row * 64 + ((c * 4 + quad) ^ (row & 7)) * 8];
      }
      __builtin_amdgcn_s_setprio(1);
      #pragma unroll
      for (int tm = 0; tm < 8; tm++)
        #pragma unroll
        for (int tn = 0; tn < 4; tn++)
          acc[tm][tn] = MFMA_BF16(af[tm], bf[tn], acc[tm][tn], 0, 0, 0);
      __builtin_amdgcn_s_setprio(0);
    }

    asm volatile("s_waitcnt lgkmcnt(0)" ::: "memory");
    __builtin_amdgcn_sched_barrier(0);
    __builtin_amdgcn_s_barrier();
    cur ^= 1;
  }

  #pragma unroll
  for (int tm = 0; tm < 8; tm++) {
    #pragma unroll
    for (int tn = 0; tn < 4; tn++) {
      const int n = n0 + wn * 64 + tn * 16 + col;
      const float bn = bias[n];
      #pragma unroll
      for (int r = 0; r < 4; r++) {
        const int m = m0 + wm * 128 + tm * 16 + quad * 4 + r;
        float v = acc[tm][tn][r] + bn;
        if (EPI == EPI_QK) {
          int nl = n & 1023, h = nl >> 6, hd = nl & 63;
          int bb = m >> 11, s2 = m & 2047;
          if (n < 1024)
            ((ushort*)outp)[(((size_t)(bb * 16 + h) * 2048 + s2) * 64) + hd] = f2bf(v * scale);
          else
            ((ushort*)outp2)[(((size_t)(bb * 16 + h) * 2048 + s2) * 64) + hd] = f2bf(v);
        } else {  // EPI_GELU
          float u = v * 0.7978845608028654f * (1.0f + 0.044715f * v * v);
          float e = __builtin_amdgcn_exp2f(u * 2.885390081777927f);  // e^{2u}
          float th = 1.0f - 2.0f * __builtin_amdgcn_rcpf(e + 1.0f);
          ((ushort*)outp)[(size_t)m * N + n] = f2bf(0.5f * v * (1.0f + th));
        }
      }
    }
  }
}

// ---------------- flash attention v12: K in LDS dbuf, V via REGISTER prefetch ----------
// Q: [BH,S,64] bf16 PRE-SCALED by log2(e)/8. K: [BH,S,64]. Vt: [BH,64,S].
// 1024 blocks = 64 heads x 16 q-tiles(128); 4 waves x 32 q (2 q-groups).
// V fragments for chunk kb+64 are ISSUED at the top of iteration kb into a second
// register set (T14 issue-early/consume-late; ping-pong via 2x-unrolled body so all
// indices are static), consumed next iteration. The barrier's vmcnt(0) drain
// guarantees landing. Removes the Vs LDS buffer: LDS = Ks 16K + P 8K = 24 KB.
__device__ __forceinline__ void attn_body(
    int kb, int cur, int prefK, int prefV,
    const ushort* __restrict__ Kg, const ushort* __restrict__ Vgl,
    int so, int col, int quad, int wave, int kvswz, int pswz,
    short8 (&qa)[2][2], short8 (&vc)[4][2], short8 (&vn)[4][2],
    f32x4 (&Ot)[2][4], float (&l_part)[2],
    ushort (*Ks)[2][64 * 32], ushort (*P_lds)[16][64]) {
  // prefetch next chunk: K -> LDS (other buf), V -> other register set
  if (prefK) {
    async_cp16(Kg + (size_t)(kb + 64) * 64,      &Ks[cur ^ 1][0][so]);
    async_cp16(Kg + (size_t)(kb + 64) * 64 + 32, &Ks[cur ^ 1][1][so]);
  }
  if (prefV) {
    #pragma unroll
    for (int dt = 0; dt < 4; dt++)
      #pragma unroll
      for (int c = 0; c < 2; c++)
        vn[dt][c] = *(const short8*)(Vgl + (size_t)(dt * 16) * 2048 + (kb + 64) + c * 32);
  }

  // K fragments from LDS (swizzled reads)
  short8 kf[4][2];
  #pragma unroll
  for (int kt = 0; kt < 4; kt++)
    #pragma unroll
    for (int c = 0; c < 2; c++)
      kf[kt][c] = *(const short8*)&Ks[cur][c][(kt * 16 + col) * 32 + (quad ^ kvswz) * 8];

  #pragma unroll
  for (int qg = 0; qg < 2; qg++) {
    f32x4 s[4];
    __builtin_amdgcn_s_setprio(1);
    #pragma unroll
    for (int kt = 0; kt < 4; kt++) {
      s[kt] = (f32x4){0.f, 0.f, 0.f, 0.f};
      s[kt] = MFMA_BF16(kf[kt][0], qa[qg][0], s[kt], 0, 0, 0);
      s[kt] = MFMA_BF16(kf[kt][1], qa[qg][1], s[kt], 0, 0, 0);
    }
    __builtin_amdgcn_s_setprio(0);
    ushort(*P)[64] = P_lds[wave];
    #pragma unroll
    for (int kt = 0; kt < 4; kt++) {
      float p0 = __builtin_amdgcn_exp2f(s[kt][0]);
      float p1 = __builtin_amdgcn_exp2f(s[kt][1]);
      float p2 = __builtin_amdgcn_exp2f(s[kt][2]);
      float p3 = __builtin_amdgcn_exp2f(s[kt][3]);
      l_part[qg] += (p0 + p1) + (p2 + p3);
      uint2 pk;
      asm("v_cvt_pk_bf16_f32 %0, %1, %2" : "=v"(pk.x) : "v"(p0), "v"(p1));
      asm("v_cvt_pk_bf16_f32 %0, %1, %2" : "=v"(pk.y) : "v"(p2), "v"(p3));
      *(uint2*)&P[col][(((2 * kt + (quad >> 1)) ^ pswz) * 8) + (quad & 1) * 4] = pk;
    }
    // PV for this qg (same-wave LDS RAW handled in-order; V from registers)
    #pragma unroll
    for (int c = 0; c < 2; c++) {
      short8 pf = *(const short8*)&P_lds[wave][col][((4 * c + quad) ^ pswz) * 8];
      __builtin_amdgcn_s_setprio(1);
      #pragma unroll
      for (int dt = 0; dt < 4; dt++)
        Ot[qg][dt] = MFMA_BF16(vc[dt][c], pf, Ot[qg][dt], 0, 0, 0);
      __builtin_amdgcn_s_setprio(0);
    }
  }
  // barrier (compiler drains vmcnt(0)/lgkmcnt(0)): prefetched K landed in LDS,
  // prefetched V landed in registers, every wave done reading Ks[cur].
  __syncthreads();
}

__global__ __launch_bounds__(256) void attn_kernel(const ushort* __restrict__ Qb,
    const ushort* __restrict__ Kb, const ushort* __restrict__ Vt,
    ushort* __restrict__ ctx) {
  const int lane = threadIdx.x & 63, wave = threadIdx.x >> 6;
  const int col = lane & 15, quad = lane >> 4;
  const int bx = blockIdx.x;
  const int bh = bx & 63;          // XCD = bh % 8 for every q-tile of this head
  const int qt = bx >> 6;          // 0..15
  const int qbase = qt * 128 + wave * 32;
  const ushort* Qh = Qb + (size_t)bh * 2048 * 64;
  const ushort* Kh = Kb + (size_t)bh * 2048 * 64;
  const ushort* Vh = Vt + (size_t)bh * 64 * 2048;

  short8 qa[2][2];
  #pragma unroll
  for (int qg = 0; qg < 2; qg++) {
    const ushort* Qr = Qh + (size_t)(qbase + qg * 16 + col) * 64 + quad * 8;
    qa[qg][0] = *(const short8*)Qr;
    qa[qg][1] = *(const short8*)(Qr + 32);
  }

  f32x4 Ot[2][4];
  float l_part[2];
  #pragma unroll
  for (int qg = 0; qg < 2; qg++) {
    l_part[qg] = 0.f;
    #pragma unroll
    for (int dt = 0; dt < 4; dt++) Ot[qg][dt] = (f32x4){0.f, 0.f, 0.f, 0.f};
  }

  __shared__ ushort Ks[2][2][64 * 32];   // [buf][d-half][key*32 + swz-chunk] 16 KB
  __shared__ ushort P_lds[4][16][64];    // [wave][q][8 x 16B chunks, swz] 8 KB

  const int lrow = lane >> 2;
  const int srow = wave * 16 + lrow;                       // row this lane stages
  const int lcol = ((lane & 3) ^ ((srow >> 1) & 3)) * 8;   // swizzled 16B chunk in 64B half
  const ushort* Kg = Kh + (size_t)srow * 64 + lcol;        // + kb*64 (+32 for half 1)
  const int so = (wave * 16) * 32;

  const int kvswz = (col >> 1) & 3;   // fragment-read XOR (rows kt*16+col: (row>>1)&3)
  const int pswz = col & 7;           // P chunk XOR

  // per-lane V fragment base: row d = dt*16+col, 16B at key offset quad*8 (+c*32+kb)
  const ushort* Vgl = Vh + (size_t)col * 2048 + quad * 8;

  // V register ping-pong sets
  short8 vA[4][2], vB[4][2];

  // prologue: stage K chunk 0 into buf 0; load V chunk 0 into vA
  async_cp16(Kg,      &Ks[0][0][so]);
  async_cp16(Kg + 32, &Ks[0][1][so]);
  #pragma unroll
  for (int dt = 0; dt < 4; dt++)
    #pragma unroll
    for (int c = 0; c < 2; c++)
      vA[dt][c] = *(const short8*)(Vgl + (size_t)(dt * 16) * 2048 + c * 32);
  __syncthreads();

  // 16 double-iterations of 128 keys (bodies alternate buf 0/1 and vA/vB)
  for (int kb = 0; kb < 2048; kb += 128) {
    const int more = (kb + 128 < 2048);
    attn_body(kb,      0, 1,    1,    Kg, Vgl, so, col, quad, wave, kvswz, pswz,
              qa, vA, vB, Ot, l_part, Ks, P_lds);
    attn_body(kb + 64, 1, more, more, Kg, Vgl, so, col, quad, wave, kvswz, pswz,
              qa, vB, vA, Ot, l_part, Ks, P_lds);
  }

  const int bb = bh >> 4, h = bh & 15;
  #pragma unroll
  for (int qg = 0; qg < 2; qg++) {
    float l = l_part[qg];
    l += __shfl_xor(l, 16);
    l += __shfl_xor(l, 32);
    float inv = __builtin_amdgcn_rcpf(l);
    const int q = qbase + qg * 16 + col;
    size_t base = ((size_t)(bb * 2048 + q)) * 1024 + h * 64;
    #pragma unroll
    for (int dt = 0; dt < 4; dt++) {
      ushort4 o;
      o.x = f2bf(Ot[qg][dt][0] * inv);
      o.y = f2bf(Ot[qg][dt][1] * inv);
      o.z = f2bf(Ot[qg][dt][2] * inv);
      o.w = f2bf(Ot[qg][dt][3] * inv);
      *(ushort4*)&ctx[base + dt * 16 + quad * 4] = o;
    }
  }
}

// ---------------- host ----------------
extern "C" void kernel_launch(void* const* d_in, const int* in_sizes, int n_in,
                              void* d_out, int out_size, void* d_ws, size_t ws_size,
                              hipStream_t stream) {
  const float* x     = (const float*)d_in[0];
  const float* Wq    = (const float*)d_in[1];
  const float* bq    = (const float*)d_in[2];
  const float* Wk    = (const float*)d_in[3];
  const float* bk    = (const float*)d_in[4];
  const float* Wv    = (const float*)d_in[5];
  const float* bv    = (const float*)d_in[6];
  const float* Wo    = (const float*)d_in[7];
  const float* bo    = (const float*)d_in[8];
  const float* W1    = (const float*)d_in[9];
  const float* b1    = (const float*)d_in[10];
  const float* W2    = (const float*)d_in[11];
  const float* b2    = (const float*)d_in[12];
  const float* ln1_g = (const float*)d_in[13];
  const float* ln1_b = (const float*)d_in[14];
  const float* ln2_g = (const float*)d_in[15];
  const float* ln2_b = (const float*)d_in[16];

  const size_t MB = 1ull << 20;
  char* ws = (char*)d_ws;
  ushort* Wqkv_b = (ushort*)(ws + 0 * MB);    // 6 MB  [3072,1024] (Q|K|V)
  ushort* Wo_b   = (ushort*)(ws + 6 * MB);    // 2 MB
  ushort* W1_b   = (ushort*)(ws + 8 * MB);    // 8 MB
  ushort* W2_b   = (ushort*)(ws + 16 * MB);   // 8 MB
  ushort* xn1    = (ushort*)(ws + 24 * MB);   // 16 MB
  ushort* Qb     = (ushort*)(ws + 40 * MB);   // 16 MB
  ushort* Kb     = (ushort*)(ws + 56 * MB);   // 16 MB
  ushort* Vt     = (ushort*)(ws + 72 * MB);   // 16 MB
  ushort* ctxb   = (ushort*)(ws + 88 * MB);   // 16 MB
  float*  x2     = (float*)(ws + 104 * MB);   // 32 MB
  ushort* xn2    = (ushort*)(ws + 136 * MB);  // 16 MB
  ushort* y1     = (ushort*)(ws + 152 * MB);  // 64 MB -> end 216 MB
  // bqkv aliases start of y1 (lifetime-disjoint: consumed before GELU GEMM writes y1)
  float*  bqkv   = (float*)(ws + 152 * MB);

  conv_all<<<12291, 256, 0, stream>>>(Wq, Wk, Wv, Wo, W1, W2, bq, bk, bv,
                                      Wqkv_b, Wo_b, W1_b, W2_b, bqkv);

  ln_kernel<<<8192, 256, 0, stream>>>(x, ln1_g, ln1_b, xn1);

  const float cs = 0.125f * 1.4426950408889634f;  // log2(e)/sqrt(64), folded into Q
  // Q|K projections (N=2048): 256^2 counted-vmcnt kernel
  gemm256_kernel<EPI_QK><<<dim3(32, 8), 512, 0, stream>>>(
      xn1, Wqkv_b, bqkv, Qb, Kb, 1024, 2048, cs);
  // V^T projection: A = Wv (rows = v-dim), B = xn (rows = tokens) -> C[vdim, token]
  gemm_kernel<EPI_VT><<<dim3(8, 64), 256, 0, stream>>>(
      Wqkv_b + (size_t)2048 * 1024, xn1, bqkv + 2048, nullptr, Vt, nullptr,
      1024, 8192, 1.0f);

  attn_kernel<<<1024, 256, 0, stream>>>(Qb, Kb, Vt, ctxb);

  gemm_kernel<EPI_WO><<<dim3(64, 8), 256, 0, stream>>>(
      ctxb, Wo_b, bo, x, x2, nullptr, 1024, 1024, 1.0f);

  ln_kernel<<<8192, 256, 0, stream>>>(x2, ln2_g, ln2_b, xn2);

  gemm256_kernel<EPI_GELU><<<dim3(32, 16), 512, 0, stream>>>(
      xn2, W1_b, b1, y1, nullptr, 1024, 4096, 1.0f);
  gemm_kernel<EPI_OUT><<<dim3(64, 8), 256, 0, stream>>>(
      y1, W2_b, b2, x2, d_out, nullptr, 4096, 1024, 1.0f);
}

// Round 8
// 510.275 us; speedup vs baseline: 1.1341x; 1.0972x over previous
//
#include <hip/hip_runtime.h>
#include <hip/hip_bf16.h>
#include <math.h>

typedef __attribute__((ext_vector_type(8))) short short8;
typedef __attribute__((ext_vector_type(4))) float f32x4;

#define MFMA_BF16 __builtin_amdgcn_mfma_f32_16x16x32_bf16

__device__ __forceinline__ ushort f2bf(float f) {
  union { __hip_bfloat16 h; ushort u; } c;
  c.h = __float2bfloat16(f);
  return c.u;
}
__device__ __forceinline__ void async_cp16(const ushort* g, ushort* l) {
  __builtin_amdgcn_global_load_lds(
      (const __attribute__((address_space(1))) void*)g,
      (__attribute__((address_space(3))) void*)l, 16, 0, 0);
}

// ------------- fused weight fp32->bf16 conversion + bias concat (one launch) -------------
__global__ __launch_bounds__(256) void conv_all(
    const float* __restrict__ Wq, const float* __restrict__ Wk,
    const float* __restrict__ Wv, const float* __restrict__ Wo,
    const float* __restrict__ W1, const float* __restrict__ W2,
    const float* __restrict__ bq, const float* __restrict__ bk,
    const float* __restrict__ bv,
    ushort* __restrict__ wqkv, ushort* __restrict__ wo,
    ushort* __restrict__ w1, ushort* __restrict__ w2,
    float* __restrict__ bqkv) {
  int i = blockIdx.x * 256 + threadIdx.x;   // float4 index
  if (i < 3145728) {
    const float* src; ushort* dst; int off;
    if (i < 786432)        { // Wq|Wk|Wv -> concatenated wqkv [3072,1024]
      dst = wqkv; off = i;
      if (i < 262144)      src = Wq + (size_t)i * 4;
      else if (i < 524288) src = Wk + (size_t)(i - 262144) * 4;
      else                 src = Wv + (size_t)(i - 524288) * 4;
    } else if (i < 1048576) { dst = wo; off = i - 786432;  src = Wo + (size_t)off * 4; }
    else if (i < 2097152)   { dst = w1; off = i - 1048576; src = W1 + (size_t)off * 4; }
    else                    { dst = w2; off = i - 2097152; src = W2 + (size_t)off * 4; }
    float4 v = *(const float4*)src;
    ushort4 o;
    o.x = f2bf(v.x); o.y = f2bf(v.y); o.z = f2bf(v.z); o.w = f2bf(v.w);
    ((ushort4*)dst)[off] = o;
  } else if (i < 3146496) {  // biases: 3 x 256 float4
    int off = i - 3145728;
    const float* src;
    if (off < 256)      src = bq + (size_t)off * 4;
    else if (off < 512) src = bk + (size_t)(off - 256) * 4;
    else                src = bv + (size_t)(off - 512) * 4;
    ((float4*)bqkv)[off] = *(const float4*)src;
  }
}

// ---------------- layernorm: one block per 1024-float row -> bf16 ----------------
__global__ __launch_bounds__(256) void ln_kernel(const float* __restrict__ x,
    const float* __restrict__ g, const float* __restrict__ b,
    ushort* __restrict__ out) {
  const int row = blockIdx.x, t = threadIdx.x;
  float4 v = ((const float4*)(x + (size_t)row * 1024))[t];
  float s  = v.x + v.y + v.z + v.w;
  float ss = v.x*v.x + v.y*v.y + v.z*v.z + v.w*v.w;
  #pragma unroll
  for (int off = 32; off >= 1; off >>= 1) {
    s  += __shfl_xor(s, off);
    ss += __shfl_xor(ss, off);
  }
  __shared__ float red[8];
  int wv = t >> 6, ln = t & 63;
  if (ln == 0) { red[wv] = s; red[4 + wv] = ss; }
  __syncthreads();
  float S  = red[0] + red[1] + red[2] + red[3];
  float SS = red[4] + red[5] + red[6] + red[7];
  float mu  = S * (1.0f/1024.0f);
  float var = SS * (1.0f/1024.0f) - mu*mu;
  float rs  = rsqrtf(var + 1e-6f);
  float4 gv = ((const float4*)g)[t];
  float4 bv = ((const float4*)b)[t];
  ushort4 o;
  o.x = f2bf((v.x-mu)*rs*gv.x + bv.x);
  o.y = f2bf((v.y-mu)*rs*gv.y + bv.y);
  o.z = f2bf((v.z-mu)*rs*gv.z + bv.z);
  o.w = f2bf((v.w-mu)*rs*gv.w + bv.w);
  ((ushort4*)(out + (size_t)row*1024))[t] = o;
}

enum { EPI_QK = 0, EPI_VT = 1, EPI_WO = 2, EPI_GELU = 3, EPI_OUT = 4 };

// ---------------- 128x128 tiled bf16 GEMM (2-barrier drain structure) ----------------
// kept for VT / WO / OUT whose shapes under-occupy a 256^2 grid
template <int EPI>
__global__ __launch_bounds__(256) void gemm_kernel(const ushort* __restrict__ A,
    const ushort* __restrict__ Bw, const float* __restrict__ bias,
    const float* __restrict__ res, void* __restrict__ outp,
    void* __restrict__ outp2, int K, int N, float scale) {
  __shared__ ushort As[2][128 * 32];
  __shared__ ushort Bs[2][128 * 32];
  const int t = threadIdx.x;
  const int m0 = blockIdx.x * 128, n0 = blockIdx.y * 128;
  const int lane = t & 63, wave = t >> 6;
  const int col = lane & 15, quad = lane >> 4;
  const int wrow = (wave >> 1) * 64, wcol = (wave & 1) * 64;

  f32x4 acc[4][4];
  #pragma unroll
  for (int i = 0; i < 4; i++)
    #pragma unroll
    for (int j = 0; j < 4; j++)
      acc[i][j] = (f32x4){0.f, 0.f, 0.f, 0.f};

  const int lrow = lane >> 2, lcol = (lane & 3) * 8;
  const ushort* Ag = A  + (size_t)(m0 + wave * 32 + lrow) * K + lcol;
  const ushort* Bg = Bw + (size_t)(n0 + wave * 32 + lrow) * K + lcol;
  const int ldso = (wave * 32) * 32;

  for (int k0 = 0; k0 < K; k0 += 64) {
    __syncthreads();
    #pragma unroll
    for (int c = 0; c < 2; c++) {
      async_cp16(Ag + k0 + c * 32,                  &As[c][ldso]);
      async_cp16(Ag + (size_t)16 * K + k0 + c * 32, &As[c][ldso + 16 * 32]);
      async_cp16(Bg + k0 + c * 32,                  &Bs[c][ldso]);
      async_cp16(Bg + (size_t)16 * K + k0 + c * 32, &Bs[c][ldso + 16 * 32]);
    }
    __syncthreads();
    #pragma unroll
    for (int c = 0; c < 2; c++) {
      short8 af[4], bf[4];
      #pragma unroll
      for (int tm = 0; tm < 4; tm++)
        af[tm] = *(const short8*)&As[c][(wrow + tm * 16 + col) * 32 + quad * 8];
      #pragma unroll
      for (int tn = 0; tn < 4; tn++)
        bf[tn] = *(const short8*)&Bs[c][(wcol + tn * 16 + col) * 32 + quad * 8];
      #pragma unroll
      for (int tm = 0; tm < 4; tm++)
        #pragma unroll
        for (int tn = 0; tn < 4; tn++)
          acc[tm][tn] = MFMA_BF16(af[tm], bf[tn], acc[tm][tn], 0, 0, 0);
    }
  }

  #pragma unroll
  for (int tm = 0; tm < 4; tm++) {
    #pragma unroll
    for (int tn = 0; tn < 4; tn++) {
      const int n = n0 + wcol + tn * 16 + col;
      const float bn = (EPI == EPI_VT) ? 0.f : bias[n];
      #pragma unroll
      for (int r = 0; r < 4; r++) {
        const int m = m0 + wrow + tm * 16 + quad * 4 + r;
        float v = acc[tm][tn][r] + bn;
        if (EPI == EPI_VT) {
          // A=Wv, Bw=xn: m = v-dim, n = token. bias indexed by m.
          float vv = v + bias[m];
          int h = m >> 6, hd = m & 63, bb = n >> 11, s2 = n & 2047;
          ((ushort*)outp)[((size_t)((bb * 16 + h) * 64 + hd)) * 2048 + s2] = f2bf(vv);
        } else if (EPI == EPI_GELU) {
          float u = v * 0.7978845608028654f * (1.0f + 0.044715f * v * v);
          float e = __builtin_amdgcn_exp2f(u * 2.885390081777927f);  // e^{2u}
          float th = 1.0f - 2.0f * __builtin_amdgcn_rcpf(e + 1.0f);
          ((ushort*)outp)[(size_t)m * N + n] = f2bf(0.5f * v * (1.0f + th));
        } else {  // EPI_WO / EPI_OUT
          ((float*)outp)[(size_t)m * N + n] = v + res[(size_t)m * N + n];
        }
      }
    }
  }
}

// ------- 256x256 bf16 GEMM, BK=64, 8 waves, 4-phase-per-tile interleaved pipeline -------
// m201-style schedule. Stage units per K-tile: A0 (rows 0-127), B0, A1 (128-255), B1 --
// one unit issued per phase into the other dbuf. Wave (wm,wn) output spans both halves:
// rows {ha*128 + wm*64 + tml*16}, cols {hb*128 + wn*32 + tnl*16}. Phase (ha,hb) order
// (0,0),(1,0),(0,1),(1,1): each reads only units staged >=3 phases earlier.
// Per-thread vmcnt ledger (2 loads/unit/thread, issue order A0,B0,A1,B1):
//   at phase-q stage-issue, outstanding = 6-8; vmcnt(4) leaves exactly the units NOT
//   needed next phase -> uniform vmcnt(4), never drains in steady state.
// Per phase: ds_read -> stage-issue -> vmcnt(4) -> barrier -> lgkmcnt(0)+sched_barrier
// -> setprio(1) -> 16 MFMA -> setprio(0) -> barrier.  (WAR: unit staged at tile t was
// last read at tile t-1, >=2 barriers earlier; reads complete via MFMA consumption.)
template <int EPI>
__global__ __launch_bounds__(512, 2) void gemm256_kernel(const ushort* __restrict__ A,
    const ushort* __restrict__ Bw, const float* __restrict__ bias,
    void* __restrict__ outp, void* __restrict__ outp2, int K, int N, float scale) {
  __shared__ ushort As[2][256 * 64];   // 32 KB per buf
  __shared__ ushort Bs[2][256 * 64];
  const int t = threadIdx.x;
  const int lane = t & 63, wave = t >> 6;
  const int col = lane & 15, quad = lane >> 4;
  const int m0 = blockIdx.x * 256, n0 = blockIdx.y * 256;
  const int wm = wave >> 2, wn = wave & 3;

  f32x4 acc[8][4];
  #pragma unroll
  for (int i = 0; i < 8; i++)
    #pragma unroll
    for (int j = 0; j < 4; j++)
      acc[i][j] = (f32x4){0.f, 0.f, 0.f, 0.f};

  // staging: unit = 128 rows x 64 cols = 2 loads/thread. chunk c = i*512+t:
  // row-in-unit r = c>>3, pos p = c&7, global chunk p^(r&7) (swizzle; (128+r)&7 == r&7).
  size_t aoff[2], boff[2];
  int d0[2];
  #pragma unroll
  for (int i = 0; i < 2; i++) {
    int c = i * 512 + t, r = c >> 3, p = c & 7;
    aoff[i] = (size_t)(m0 + r) * K + (p ^ (r & 7)) * 8;
    boff[i] = (size_t)(n0 + r) * K + (p ^ (r & 7)) * 8;
    d0[i] = c * 8;
  }
  const size_t up = (size_t)128 * K;   // row offset for A1/B1 units

  const int NT = K >> 6;
  // prologue: stage tile 0, unit order A0,B0,A1,B1; wait A0,B0 (A1,B1 in flight)
  #pragma unroll
  for (int i = 0; i < 2; i++) async_cp16(A  + aoff[i],      &As[0][d0[i]]);
  #pragma unroll
  for (int i = 0; i < 2; i++) async_cp16(Bw + boff[i],      &Bs[0][d0[i]]);
  #pragma unroll
  for (int i = 0; i < 2; i++) async_cp16(A  + aoff[i] + up, &As[0][8192 + d0[i]]);
  #pragma unroll
  for (int i = 0; i < 2; i++) async_cp16(Bw + boff[i] + up, &Bs[0][8192 + d0[i]]);
  asm volatile("s_waitcnt vmcnt(4)" ::: "memory");
  __builtin_amdgcn_sched_barrier(0);
  __builtin_amdgcn_s_barrier();
  __builtin_amdgcn_sched_barrier(0);

  short8 af[4][2], bf[2][2];
  for (int kt = 0; kt < NT; kt++) {
    const int cur = kt & 1, nxt = cur ^ 1;
    const size_t ko = (size_t)(kt + 1) << 6;
    const bool more = (kt + 1 < NT);
    #pragma unroll
    for (int ph = 0; ph < 4; ph++) {
      const int ha = ph & 1;    // 0,1,0,1
      const int hb = ph >> 1;   // 0,0,1,1
      // ds_read: af every phase; bf when hb changes (ph 0 and 2)
      #pragma unroll
      for (int tml = 0; tml < 4; tml++) {
        const int row = ha * 128 + wm * 64 + tml * 16 + col;
        #pragma unroll
        for (int c = 0; c < 2; c++)
          af[tml][c] = *(const short8*)&As[cur][row * 64 + (((c * 4 + quad) ^ (row & 7)) * 8)];
      }
      if (ph == 0 || ph == 2) {
        #pragma unroll
        for (int tnl = 0; tnl < 2; tnl++) {
          const int row = hb * 128 + wn * 32 + tnl * 16 + col;
          #pragma unroll
          for (int c = 0; c < 2; c++)
            bf[tnl][c] = *(const short8*)&Bs[cur][row * 64 + (((c * 4 + quad) ^ (row & 7)) * 8)];
        }
      }
      // stage unit 'ph' of tile kt+1 into the other dbuf
      if (more) {
        if (ph == 0) {
          #pragma unroll
          for (int i = 0; i < 2; i++) async_cp16(A  + aoff[i] + ko,      &As[nxt][d0[i]]);
        } else if (ph == 1) {
          #pragma unroll
          for (int i = 0; i < 2; i++) async_cp16(Bw + boff[i] + ko,      &Bs[nxt][d0[i]]);
        } else if (ph == 2) {
          #pragma unroll
          for (int i = 0; i < 2; i++) async_cp16(A  + aoff[i] + up + ko, &As[nxt][8192 + d0[i]]);
        } else {
          #pragma unroll
          for (int i = 0; i < 2; i++) async_cp16(Bw + boff[i] + up + ko, &Bs[nxt][8192 + d0[i]]);
        }
        asm volatile("s_waitcnt vmcnt(4)" ::: "memory");
      } else {
        if (ph == 0)      asm volatile("s_waitcnt vmcnt(2)" ::: "memory");
        else              asm volatile("s_waitcnt vmcnt(0)" ::: "memory");
      }
      __builtin_amdgcn_sched_barrier(0);
      __builtin_amdgcn_s_barrier();
      asm volatile("s_waitcnt lgkmcnt(0)" ::: "memory");
      __builtin_amdgcn_sched_barrier(0);
      __builtin_amdgcn_s_setprio(1);
      #pragma unroll
      for (int tml = 0; tml < 4; tml++)
        #pragma unroll
        for (int tnl = 0; tnl < 2; tnl++) {
          acc[ha*4+tml][hb*2+tnl] = MFMA_BF16(af[tml][0], bf[tnl][0], acc[ha*4+tml][hb*2+tnl], 0, 0, 0);
          acc[ha*4+tml][hb*2+tnl] = MFMA_BF16(af[tml][1], bf[tnl][1], acc[ha*4+tml][hb*2+tnl], 0, 0, 0);
        }
      __builtin_amdgcn_s_setprio(0);
      __builtin_amdgcn_sched_barrier(0);
      __builtin_amdgcn_s_barrier();
      __builtin_amdgcn_sched_barrier(0);
    }
  }

  #pragma unroll
  for (int tm = 0; tm < 8; tm++) {
    const int ha = tm >> 2, tml = tm & 3;
    #pragma unroll
    for (int tn = 0; tn < 4; tn++) {
      const int hb = tn >> 1, tnl = tn & 1;
      const int n = n0 + hb * 128 + wn * 32 + tnl * 16 + col;
      const float bn = bias[n];
      #pragma unroll
      for (int r = 0; r < 4; r++) {
        const int m = m0 + ha * 128 + wm * 64 + tml * 16 + quad * 4 + r;
        float v = acc[tm][tn][r] + bn;
        if (EPI == EPI_QK) {
          int nl = n & 1023, h = nl >> 6, hd = nl & 63;
          int bb = m >> 11, s2 = m & 2047;
          if (n < 1024)
            ((ushort*)outp)[(((size_t)(bb * 16 + h) * 2048 + s2) * 64) + hd] = f2bf(v * scale);
          else
            ((ushort*)outp2)[(((size_t)(bb * 16 + h) * 2048 + s2) * 64) + hd] = f2bf(v);
        } else {  // EPI_GELU
          float u = v * 0.7978845608028654f * (1.0f + 0.044715f * v * v);
          float e = __builtin_amdgcn_exp2f(u * 2.885390081777927f);  // e^{2u}
          float th = 1.0f - 2.0f * __builtin_amdgcn_rcpf(e + 1.0f);
          ((ushort*)outp)[(size_t)m * N + n] = f2bf(0.5f * v * (1.0f + th));
        }
      }
    }
  }
}

// ---------------- flash attention v11 (R5 proven, 113 us) ----------
__global__ __launch_bounds__(256) void attn_kernel(const ushort* __restrict__ Qb,
    const ushort* __restrict__ Kb, const ushort* __restrict__ Vt,
    ushort* __restrict__ ctx) {
  const int lane = threadIdx.x & 63, wave = threadIdx.x >> 6;
  const int col = lane & 15, quad = lane >> 4;
  const int bx = blockIdx.x;
  const int bh = bx & 63;          // XCD = bh % 8 for every q-tile of this head
  const int qt = bx >> 6;          // 0..15
  const int qbase = qt * 128 + wave * 32;
  const ushort* Qh = Qb + (size_t)bh * 2048 * 64;
  const ushort* Kh = Kb + (size_t)bh * 2048 * 64;
  const ushort* Vh = Vt + (size_t)bh * 64 * 2048;

  short8 qa[2][2];
  #pragma unroll
  for (int qg = 0; qg < 2; qg++) {
    const ushort* Qr = Qh + (size_t)(qbase + qg * 16 + col) * 64 + quad * 8;
    qa[qg][0] = *(const short8*)Qr;
    qa[qg][1] = *(const short8*)(Qr + 32);
  }

  f32x4 Ot[2][4];
  float l_part[2];
  #pragma unroll
  for (int qg = 0; qg < 2; qg++) {
    l_part[qg] = 0.f;
    #pragma unroll
    for (int dt = 0; dt < 4; dt++) Ot[qg][dt] = (f32x4){0.f, 0.f, 0.f, 0.f};
  }

  __shared__ ushort Ks[2][2][64 * 32];   // [buf][d-half][key*32 + swz-chunk] 16 KB
  __shared__ ushort Vs[2][2][64 * 32];   // [buf][key-half][d*32 + swz-chunk] 16 KB
  __shared__ ushort P_lds[4][16][64];    // [wave][q][8 x 16B chunks, swz] 8 KB

  const int lrow = lane >> 2;
  const int srow = wave * 16 + lrow;                       // row this lane stages
  const int lcol = ((lane & 3) ^ ((srow >> 1) & 3)) * 8;   // swizzled 16B chunk in 64B half
  const ushort* Kg = Kh + (size_t)srow * 64 + lcol;        // + kb*64 (+32 for half 1)
  const ushort* Vg = Vh + (size_t)srow * 2048 + lcol;      // + kb   (+32 for half 1)
  const int so = (wave * 16) * 32;

  const int kvswz = (col >> 1) & 3;   // fragment-read XOR (rows kt*16+col: (row>>1)&3)
  const int pswz = col & 7;           // P chunk XOR

  // prologue: stage chunk 0 into buf 0
  async_cp16(Kg,      &Ks[0][0][so]);
  async_cp16(Kg + 32, &Ks[0][1][so]);
  async_cp16(Vg,      &Vs[0][0][so]);
  async_cp16(Vg + 32, &Vs[0][1][so]);
  __syncthreads();

  int cur = 0;
  for (int kb = 0; kb < 2048; kb += 64) {
    if (kb + 64 < 2048) {
      const int nxt = cur ^ 1;
      async_cp16(Kg + (size_t)(kb + 64) * 64,      &Ks[nxt][0][so]);
      async_cp16(Kg + (size_t)(kb + 64) * 64 + 32, &Ks[nxt][1][so]);
      async_cp16(Vg + (kb + 64),                   &Vs[nxt][0][so]);
      async_cp16(Vg + (kb + 64) + 32,              &Vs[nxt][1][so]);
    }

    // fragments from LDS (shared across the 2 q-groups), swizzled reads
    short8 kf[4][2], vf[4][2];
    #pragma unroll
    for (int kt = 0; kt < 4; kt++)
      #pragma unroll
      for (int c = 0; c < 2; c++)
        kf[kt][c] = *(const short8*)&Ks[cur][c][(kt * 16 + col) * 32 + (quad ^ kvswz) * 8];
    #pragma unroll
    for (int dt = 0; dt < 4; dt++)
      #pragma unroll
      for (int c = 0; c < 2; c++)
        vf[dt][c] = *(const short8*)&Vs[cur][c][(dt * 16 + col) * 32 + (quad ^ kvswz) * 8];

    #pragma unroll
    for (int qg = 0; qg < 2; qg++) {
      f32x4 s[4];
      __builtin_amdgcn_s_setprio(1);
      #pragma unroll
      for (int kt = 0; kt < 4; kt++) {
        s[kt] = (f32x4){0.f, 0.f, 0.f, 0.f};
        s[kt] = MFMA_BF16(kf[kt][0], qa[qg][0], s[kt], 0, 0, 0);
        s[kt] = MFMA_BF16(kf[kt][1], qa[qg][1], s[kt], 0, 0, 0);
      }
      __builtin_amdgcn_s_setprio(0);
      ushort(*P)[64] = P_lds[wave];
      #pragma unroll
      for (int kt = 0; kt < 4; kt++) {
        float p0 = __builtin_amdgcn_exp2f(s[kt][0]);
        float p1 = __builtin_amdgcn_exp2f(s[kt][1]);
        float p2 = __builtin_amdgcn_exp2f(s[kt][2]);
        float p3 = __builtin_amdgcn_exp2f(s[kt][3]);
        l_part[qg] += (p0 + p1) + (p2 + p3);
        uint2 pk;
        asm("v_cvt_pk_bf16_f32 %0, %1, %2" : "=v"(pk.x) : "v"(p0), "v"(p1));
        asm("v_cvt_pk_bf16_f32 %0, %1, %2" : "=v"(pk.y) : "v"(p2), "v"(p3));
        *(uint2*)&P[col][(((2 * kt + (quad >> 1)) ^ pswz) * 8) + (quad & 1) * 4] = pk;
      }
      // PV for this qg (same-wave LDS RAW handled in-order; no barrier needed)
      #pragma unroll
      for (int c = 0; c < 2; c++) {
        short8 pf = *(const short8*)&P_lds[wave][col][((4 * c + quad) ^ pswz) * 8];
        __builtin_amdgcn_s_setprio(1);
        #pragma unroll
        for (int dt = 0; dt < 4; dt++)
          Ot[qg][dt] = MFMA_BF16(vf[dt][c], pf, Ot[qg][dt], 0, 0, 0);
        __builtin_amdgcn_s_setprio(0);
      }
    }
    __syncthreads();
    cur ^= 1;
  }

  const int bb = bh >> 4, h = bh & 15;
  #pragma unroll
  for (int qg = 0; qg < 2; qg++) {
    float l = l_part[qg];
    l += __shfl_xor(l, 16);
    l += __shfl_xor(l, 32);
    float inv = __builtin_amdgcn_rcpf(l);
    const int q = qbase + qg * 16 + col;
    size_t base = ((size_t)(bb * 2048 + q)) * 1024 + h * 64;
    #pragma unroll
    for (int dt = 0; dt < 4; dt++) {
      ushort4 o;
      o.x = f2bf(Ot[qg][dt][0] * inv);
      o.y = f2bf(Ot[qg][dt][1] * inv);
      o.z = f2bf(Ot[qg][dt][2] * inv);
      o.w = f2bf(Ot[qg][dt][3] * inv);
      *(ushort4*)&ctx[base + dt * 16 + quad * 4] = o;
    }
  }
}

// ---------------- host ----------------
extern "C" void kernel_launch(void* const* d_in, const int* in_sizes, int n_in,
                              void* d_out, int out_size, void* d_ws, size_t ws_size,
                              hipStream_t stream) {
  const float* x     = (const float*)d_in[0];
  const float* Wq    = (const float*)d_in[1];
  const float* bq    = (const float*)d_in[2];
  const float* Wk    = (const float*)d_in[3];
  const float* bk    = (const float*)d_in[4];
  const float* Wv    = (const float*)d_in[5];
  const float* bv    = (const float*)d_in[6];
  const float* Wo    = (const float*)d_in[7];
  const float* bo    = (const float*)d_in[8];
  const float* W1    = (const float*)d_in[9];
  const float* b1    = (const float*)d_in[10];
  const float* W2    = (const float*)d_in[11];
  const float* b2    = (const float*)d_in[12];
  const float* ln1_g = (const float*)d_in[13];
  const float* ln1_b = (const float*)d_in[14];
  const float* ln2_g = (const float*)d_in[15];
  const float* ln2_b = (const float*)d_in[16];

  const size_t MB = 1ull << 20;
  char* ws = (char*)d_ws;
  ushort* Wqkv_b = (ushort*)(ws + 0 * MB);    // 6 MB  [3072,1024] (Q|K|V)
  ushort* Wo_b   = (ushort*)(ws + 6 * MB);    // 2 MB
  ushort* W1_b   = (ushort*)(ws + 8 * MB);    // 8 MB
  ushort* W2_b   = (ushort*)(ws + 16 * MB);   // 8 MB
  ushort* xn1    = (ushort*)(ws + 24 * MB);   // 16 MB
  ushort* Qb     = (ushort*)(ws + 40 * MB);   // 16 MB
  ushort* Kb     = (ushort*)(ws + 56 * MB);   // 16 MB
  ushort* Vt     = (ushort*)(ws + 72 * MB);   // 16 MB
  ushort* ctxb   = (ushort*)(ws + 88 * MB);   // 16 MB
  float*  x2     = (float*)(ws + 104 * MB);   // 32 MB
  ushort* xn2    = (ushort*)(ws + 136 * MB);  // 16 MB
  ushort* y1     = (ushort*)(ws + 152 * MB);  // 64 MB -> end 216 MB
  // bqkv aliases start of y1 (lifetime-disjoint: consumed before GELU GEMM writes y1)
  float*  bqkv   = (float*)(ws + 152 * MB);

  conv_all<<<12291, 256, 0, stream>>>(Wq, Wk, Wv, Wo, W1, W2, bq, bk, bv,
                                      Wqkv_b, Wo_b, W1_b, W2_b, bqkv);

  ln_kernel<<<8192, 256, 0, stream>>>(x, ln1_g, ln1_b, xn1);

  const float cs = 0.125f * 1.4426950408889634f;  // log2(e)/sqrt(64), folded into Q
  // Q|K projections (N=2048): 256^2 4-phase pipeline
  gemm256_kernel<EPI_QK><<<dim3(32, 8), 512, 0, stream>>>(
      xn1, Wqkv_b, bqkv, Qb, Kb, 1024, 2048, cs);
  // V^T projection: A = Wv (rows = v-dim), B = xn (rows = tokens) -> C[vdim, token]
  gemm_kernel<EPI_VT><<<dim3(8, 64), 256, 0, stream>>>(
      Wqkv_b + (size_t)2048 * 1024, xn1, bqkv + 2048, nullptr, Vt, nullptr,
      1024, 8192, 1.0f);

  attn_kernel<<<1024, 256, 0, stream>>>(Qb, Kb, Vt, ctxb);

  gemm_kernel<EPI_WO><<<dim3(64, 8), 256, 0, stream>>>(
      ctxb, Wo_b, bo, x, x2, nullptr, 1024, 1024, 1.0f);

  ln_kernel<<<8192, 256, 0, stream>>>(x2, ln2_g, ln2_b, xn2);

  gemm256_kernel<EPI_GELU><<<dim3(32, 16), 512, 0, stream>>>(
      xn2, W1_b, b1, y1, nullptr, 1024, 4096, 1.0f);
  gemm_kernel<EPI_OUT><<<dim3(64, 8), 256, 0, stream>>>(
      y1, W2_b, b2, x2, d_out, nullptr, 4096, 1024, 1.0f);
}